// Round 22
// baseline (184.060 us; speedup 1.0000x reference)
//
#include <hip/hip_runtime.h>
#include <hip/hip_bf16.h>

typedef unsigned short u16;
typedef __attribute__((ext_vector_type(8))) short short8v;   // 8 bf16 = 4 VGPR
typedef __attribute__((ext_vector_type(4))) float f32x4;     // mfma 16x16 acc
typedef __attribute__((ext_vector_type(16))) float f32x16;   // mfma 32x32 acc

#define Bb 4
#define Tt 2048
#define Cc 1024
#define Hh 16
#define C3 3072
#define Mm 8192

__device__ __forceinline__ u16 f2bf(float f) {
    union { __hip_bfloat16 h; u16 u; } r;
    r.h = __float2bfloat16(f);
    return r.u;
}
__device__ __forceinline__ unsigned int pk2(float a, float b) {
    union { __hip_bfloat162 h; unsigned int u; } r;
    r.h.x = __float2bfloat16(a);
    r.h.y = __float2bfloat16(b);
    return r.u;
}
__device__ __forceinline__ float exp2g(float x) {
#if __has_builtin(__builtin_amdgcn_exp2f)
    return __builtin_amdgcn_exp2f(x);
#else
    return exp2f(x);
#endif
}
__device__ __forceinline__ void plswap(unsigned int& a, unsigned int& b) {
#if __has_builtin(__builtin_amdgcn_permlane32_swap)
    typedef __attribute__((ext_vector_type(2))) unsigned int uint2v;
    uint2v r = __builtin_amdgcn_permlane32_swap(a, b, false, false);
    a = r.x; b = r.y;
#else
    asm volatile("v_permlane32_swap_b32 %0, %1" : "+v"(a), "+v"(b));
#endif
}
// global -> LDS direct (16B/lane). LDS dest: wave-uniform base + lane*16.
__device__ __forceinline__ void gload16(const void* g, void* l) {
    __builtin_amdgcn_global_load_lds(
        (const __attribute__((address_space(1))) unsigned int*)g,
        (__attribute__((address_space(3))) unsigned int*)l, 16, 0, 0);
}
// scale 8 bf16 by constant (unpack -> mul -> repack), used once per block
__device__ __forceinline__ short8v scale8(short8v v, float s) {
    union { short8v sv; unsigned int u[4]; } in, out;
    in.sv = v;
#pragma unroll
    for (int i = 0; i < 4; ++i) {
        float lo = __uint_as_float(in.u[i] << 16);
        float hi = __uint_as_float(in.u[i] & 0xffff0000u);
        out.u[i] = pk2(lo * s, hi * s);
    }
    return out.sv;
}

// ---------- merged preprocessing: cvt_x + wtrans(Wqkv) + wtrans(Wout) ----------
__global__ __launch_bounds__(256) void prep(const float* __restrict__ x,
                                            u16* __restrict__ xbf,
                                            const float* __restrict__ Wqkv,
                                            u16* __restrict__ WqkvT,
                                            const float* __restrict__ Wout,
                                            u16* __restrict__ WoutT) {
    __shared__ float t[32][33];
    const int blk = blockIdx.x;
    if (blk < 8192) {
        int i = blk * 256 + threadIdx.x;
        float4 v = reinterpret_cast<const float4*>(x)[i];
        ushort4 o;
        o.x = f2bf(v.x); o.y = f2bf(v.y); o.z = f2bf(v.z); o.w = f2bf(v.w);
        reinterpret_cast<ushort4*>(xbf)[i] = o;
        return;
    }
    const float* in;
    u16* out;
    int R, Ccols, bx, by;
    if (blk < 8192 + 3072) {
        const int idx = blk - 8192;
        in = Wqkv; out = WqkvT; R = Cc; Ccols = C3;
        bx = idx % 96; by = idx / 96;
    } else {
        const int idx = blk - (8192 + 3072);
        in = Wout; out = WoutT; R = Cc; Ccols = Cc;
        bx = idx & 31; by = idx >> 5;
    }
    const int tx = threadIdx.x & 31, ty = threadIdx.x >> 5;  // 32x8
    const int c = bx * 32 + tx;
#pragma unroll
    for (int j = 0; j < 4; ++j) {
        int r = by * 32 + ty + j * 8;
        t[ty + j * 8][tx] = in[(size_t)r * Ccols + c];
    }
    __syncthreads();
#pragma unroll
    for (int j = 0; j < 4; ++j) {
        int orow = bx * 32 + ty + j * 8;
        int oc   = by * 32 + tx;
        out[(size_t)orow * R + oc] = f2bf(t[tx][ty + j * 8]);
    }
}

// ---------- 128x128 MFMA GEMM (m97 structure) — GEMM2, scalar epilogue ----------
template <int OUTF32>
__global__ __launch_bounds__(256) void gemm_mfma(const u16* __restrict__ A,
                                                 const u16* __restrict__ BT,
                                                 void* __restrict__ C0,
                                                 int M, int N, int K) {
    __shared__ u16 As[128 * 32];
    __shared__ u16 Bs[128 * 32];
    const int tid = threadIdx.x;
    const int w = tid >> 6, l = tid & 63;
    const int wr = w >> 1, wc = w & 1;
    const int g = l >> 4, q = l & 15;
    const int bm = blockIdx.x * 128, bn = blockIdx.y * 128;
    const int lrow = l >> 2;
    const int lcol = (l & 3) * 8;

    f32x4 acc[4][4] = {};
    const u16* Ap = A + (size_t)(bm + w * 32 + lrow) * K + lcol;
    const u16* Bp = BT + (size_t)(bn + w * 32 + lrow) * K + lcol;

    for (int k0 = 0; k0 < K; k0 += 32) {
        gload16(Ap + k0, &As[(w * 32) * 32]);
        gload16(Ap + (size_t)16 * K + k0, &As[(w * 32 + 16) * 32]);
        gload16(Bp + k0, &Bs[(w * 32) * 32]);
        gload16(Bp + (size_t)16 * K + k0, &Bs[(w * 32 + 16) * 32]);
        __syncthreads();
        short8v af[4], bf[4];
#pragma unroll
        for (int m = 0; m < 4; ++m)
            af[m] = *reinterpret_cast<const short8v*>(&As[(wr * 64 + m * 16 + q) * 32 + g * 8]);
#pragma unroll
        for (int n = 0; n < 4; ++n)
            bf[n] = *reinterpret_cast<const short8v*>(&Bs[(wc * 64 + n * 16 + q) * 32 + g * 8]);
#pragma unroll
        for (int m = 0; m < 4; ++m)
#pragma unroll
            for (int n = 0; n < 4; ++n)
                acc[m][n] = __builtin_amdgcn_mfma_f32_16x16x32_bf16(af[m], bf[n], acc[m][n], 0, 0, 0);
        __syncthreads();
    }

#pragma unroll
    for (int m = 0; m < 4; ++m)
#pragma unroll
        for (int n = 0; n < 4; ++n)
#pragma unroll
            for (int r = 0; r < 4; ++r) {
                int row = bm + wr * 64 + m * 16 + g * 4 + r;
                int col = bn + wc * 64 + n * 16 + q;
                if (OUTF32)
                    reinterpret_cast<float*>(C0)[(size_t)row * N + col] = acc[m][n][r];
                else
                    reinterpret_cast<u16*>(C0)[(size_t)row * N + col] = f2bf(acc[m][n][r]);
            }
}

// ---------- 256x256 BK=64 8-wave GEMM, 4-sub-phase interleave (r18 verified) ----
__global__ __launch_bounds__(512, 2) void gemm256_qkv(const u16* __restrict__ A,
                                                      const u16* __restrict__ BT,
                                                      u16* __restrict__ qkOut,
                                                      u16* __restrict__ vTOut,
                                                      int K) {
    __shared__ u16 SM[65536];   // 128 KiB
    const int tid = threadIdx.x;
    const int wv = tid >> 6, L = tid & 63;
    const int wm = wv >> 2, wn = wv & 3;        // 2 x 4 waves
    const int q = L & 15, g = L >> 4;
    const int bm = blockIdx.x * 256, bn = blockIdx.y * 256;
    const int nK = K >> 6;

    char* smB = (char*)SM;
    const int srow = wv * 16 + (L >> 3);
    const int scol = ((L & 7) ^ ((L >> 3) & 7)) * 8;   // u16 (inverse swizzle on src)
    const u16* Asrc = A + (size_t)(bm + srow) * K + scol;
    const u16* Bsrc = BT + (size_t)(bn + srow) * K + scol;

#define STG2(src, ldsByte)                                                \
    { gload16((src), smB + (ldsByte) + wv * 2048);                        \
      gload16((src) + 8 * (size_t)K, smB + (ldsByte) + wv * 2048 + 1024); }

    // prologue: K0 {A0,A1,B0,B1} -> buf0 ; K1 {A0,A1,B0} -> buf1
    STG2(Asrc, 0)
    STG2(Asrc + 128 * (size_t)K, 16384)
    STG2(Bsrc, 32768)
    STG2(Bsrc + 128 * (size_t)K, 49152)
    STG2(Asrc + 64, 65536)
    STG2(Asrc + 128 * (size_t)K + 64, 65536 + 16384)
    STG2(Bsrc + 64, 65536 + 32768)

    const int rA = (wm * 128 + q) * 64;
    const int rB = 16384 + (wn * 64 + q) * 64;
    const int s0 = (g ^ (q & 7)) * 8;           // ks=0 slot
    const int s1 = ((4 + g) ^ (q & 7)) * 8;     // ks=1 slot

    f32x4 acc[8][4] = {};

#define LDA2(dst, mf)                                                                   \
    dst[0] = *reinterpret_cast<const short8v*>(&SM[bufU + rA + mf * 1024 + s0]);        \
    dst[1] = *reinterpret_cast<const short8v*>(&SM[bufU + rA + mf * 1024 + s1]);
#define LDB2(nf)                                                                        \
    Bf##nf[0] = *reinterpret_cast<const short8v*>(&SM[bufU + rB + nf * 1024 + s0]);     \
    Bf##nf[1] = *reinterpret_cast<const short8v*>(&SM[bufU + rB + nf * 1024 + s1]);
#define MMA2(Aa, nf, ia)                                                                       \
    acc[ia][nf] = __builtin_amdgcn_mfma_f32_16x16x32_bf16(Aa[0], Bf##nf[0], acc[ia][nf], 0, 0, 0); \
    acc[ia][nf] = __builtin_amdgcn_mfma_f32_16x16x32_bf16(Aa[1], Bf##nf[1], acc[ia][nf], 0, 0, 0);
#define MBLK2(Aa, Ab, ia, ib)                                             \
    __builtin_amdgcn_s_setprio(1);                                        \
    MMA2(Aa, 0, ia) MMA2(Aa, 1, ia) MMA2(Aa, 2, ia) MMA2(Aa, 3, ia)       \
    MMA2(Ab, 0, ib) MMA2(Ab, 1, ib) MMA2(Ab, 2, ib) MMA2(Ab, 3, ib)       \
    __builtin_amdgcn_s_setprio(0);

    for (int t = 0; t < nK; ++t) {
        const int bufU = (t & 1) * 32768;
        const int curB = (t & 1) * 65536;
        const int nxtB = ((t + 1) & 1) * 65536;
        if (t == nK - 1) { asm volatile("s_waitcnt vmcnt(0)" ::: "memory"); }
        else             { asm volatile("s_waitcnt vmcnt(6)" ::: "memory"); }
        __builtin_amdgcn_s_barrier();
        __builtin_amdgcn_sched_barrier(0);

        short8v Bf0[2], Bf1[2], Bf2[2], Bf3[2];
        LDB2(0) LDB2(1) LDB2(2) LDB2(3)
        short8v Af0[2], Af1[2];
        LDA2(Af0, 0) LDA2(Af1, 1)
        if (t + 1 < nK) STG2(Bsrc + 128 * (size_t)K + (t + 1) * 64, nxtB + 49152)
        __builtin_amdgcn_sched_barrier(0);
        MBLK2(Af0, Af1, 0, 1)
        __builtin_amdgcn_sched_barrier(0);

        short8v Af2[2], Af3[2];
        LDA2(Af2, 2) LDA2(Af3, 3)
        __builtin_amdgcn_sched_barrier(0);
        MBLK2(Af2, Af3, 2, 3)
        __builtin_amdgcn_sched_barrier(0);

        short8v Af4[2], Af5[2];
        LDA2(Af4, 4) LDA2(Af5, 5)
        __builtin_amdgcn_sched_barrier(0);
        MBLK2(Af4, Af5, 4, 5)
        __builtin_amdgcn_sched_barrier(0);

        short8v Af6[2], Af7[2];
        LDA2(Af6, 6) LDA2(Af7, 7)
        asm volatile("s_waitcnt lgkmcnt(0)" ::: "memory");
        __builtin_amdgcn_sched_barrier(0);
        __builtin_amdgcn_s_barrier();
        if (t + 2 < nK) {
            STG2(Asrc + (t + 2) * 64, curB)
            STG2(Asrc + 128 * (size_t)K + (t + 2) * 64, curB + 16384)
            STG2(Bsrc + (t + 2) * 64, curB + 32768)
        }
        __builtin_amdgcn_sched_barrier(0);
        MBLK2(Af6, Af7, 6, 7)
    }
#undef MMA2
#undef MBLK2
#undef LDA2
#undef LDB2
#undef STG2

    // ---- epilogue ----
    __builtin_amdgcn_s_barrier();   // all waves past final LDS reads
    if (bn < 2048) {
        char* smb2 = (char*)SM;
#pragma unroll
        for (int mf = 0; mf < 8; ++mf) {
            const int row = wm * 128 + mf * 16 + g * 4;
#pragma unroll
            for (int nf = 0; nf < 4; ++nf) {
                const int col = wn * 64 + nf * 16 + q;
#pragma unroll
                for (int rr = 0; rr < 4; ++rr) {
                    const int r2 = row + rr;
                    *(u16*)(smb2 + r2 * 512 + ((((col >> 3) ^ (r2 & 7))) << 4) + (col & 7) * 2)
                        = f2bf(acc[mf][nf][rr]);
                }
            }
        }
        __syncthreads();
        const int erow = tid >> 1;
        const int ebase = (tid & 1) * 16;
        u16* orow = qkOut + (size_t)(bm + erow) * 2048 + bn;
#pragma unroll
        for (int j = 0; j < 16; ++j) {
            const int s = ebase + j;
            uint4 v = *(const uint4*)(smb2 + erow * 512 + ((s ^ (erow & 7)) << 4));
            *reinterpret_cast<uint4*>(orow + s * 8) = v;
        }
    } else {
        const int colb = bn - 2048 + wn * 64;
        const int bI = bm >> 11;
        const int tIb = (bm & 2047) + wm * 128 + g * 4;
#pragma unroll
        for (int mf = 0; mf < 8; ++mf)
#pragma unroll
            for (int nf = 0; nf < 4; ++nf) {
                const int col = colb + nf * 16 + q;
                uint2 pv;
                pv.x = pk2(acc[mf][nf][0], acc[mf][nf][1]);
                pv.y = pk2(acc[mf][nf][2], acc[mf][nf][3]);
                *reinterpret_cast<uint2*>(
                    &vTOut[((size_t)bI * 1024 + col) * 2048 + tIb + mf * 16]) = pv;
            }
    }
}

// ---------- MFMA flash attention (causal), static-max softmax ----------
// 1024 blocks, one 128-q chunk each, LPT order. KVBLK=128 (nsteps=chunk+1):
// K [128][72] + V^T [64][136] single-buffered (35.8KB, 4 blocks/CU),
// reg-prefetch of next tile, 2 barriers per 128-key step (halved barriers).
__global__ __launch_bounds__(256) void attn_mfma(const u16* __restrict__ qk,
                                                 const u16* __restrict__ vT,
                                                 u16* __restrict__ y) {
    __shared__ u16 SM[17920];   // 35,840 B: K [128][72] @0 | V^T [64][136] @9216
    const int tid = threadIdx.x;
    const int w = tid >> 6, l = tid & 63;
    const int q31 = l & 31, hi = l >> 5;
    const int bid = blockIdx.x;
    const int bh = bid & 63;
    const int chunk = 15 - (bid >> 6);        // LPT: big chunks first
    const int b = bh >> 4, h = bh & 15;
    const size_t tok0 = (size_t)b * Tt;

    const float C2 = 0.18033688011112042f;   // 0.125 * log2(e), folded into Q

    // K staging: 2 thr/row x 32 u16 (4 uint4)
    const int kRow = tid >> 1, kSeg = (tid & 1) * 32;
    const int soffK = kRow * 72 + kSeg;
    const u16* gK = qk + (tok0 + kRow) * 2048 + 1024 + h * 64 + kSeg;
    // V staging: 4 thr/row x 32 keys (4 uint4)
    const int vRow = tid >> 2, vSeg = (tid & 3) * 32;
    const int soffV = 9216 + vRow * 136 + vSeg;
    const u16* gV = vT + ((size_t)b * 1024 + h * 64 + vRow) * 2048 + vSeg;

    const int nsteps = chunk + 1;
    const int q0w = chunk * 128 + w * 32;
    const int qlane = q0w + q31;

    short8v qf0, qf1, qf2, qf3;
    {
        const u16* qp = qk + (tok0 + qlane) * 2048 + h * 64 + hi * 8;
        qf0 = scale8(*reinterpret_cast<const short8v*>(qp), C2);
        qf1 = scale8(*reinterpret_cast<const short8v*>(qp + 16), C2);
        qf2 = scale8(*reinterpret_cast<const short8v*>(qp + 32), C2);
        qf3 = scale8(*reinterpret_cast<const short8v*>(qp + 48), C2);
    }

    f32x16 acc0 = {}, acc1 = {};
    float l_run = 0.f;

    {   // prologue: stage tile 0
#pragma unroll
        for (int j = 0; j < 4; ++j) {
            uint4 kv = *reinterpret_cast<const uint4*>(gK + j * 8);
            uint4 vv = *reinterpret_cast<const uint4*>(gV + j * 8);
            *reinterpret_cast<uint4*>(&SM[soffK + j * 8]) = kv;
            *reinterpret_cast<uint4*>(&SM[soffV + j * 8]) = vv;
        }
    }
    __syncthreads();

    for (int t = 0; t < nsteps; ++t) {
        const bool pre = (t + 1 < nsteps);
        uint4 kr0 = {}, kr1 = {}, kr2 = {}, kr3 = {};
        uint4 vr0 = {}, vr1 = {}, vr2 = {}, vr3 = {};
        if (pre) {
            const u16* gKt = gK + (size_t)(t + 1) * 128 * 2048;
            const u16* gVt = gV + (t + 1) * 128;
            kr0 = *reinterpret_cast<const uint4*>(gKt);
            kr1 = *reinterpret_cast<const uint4*>(gKt + 8);
            kr2 = *reinterpret_cast<const uint4*>(gKt + 16);
            kr3 = *reinterpret_cast<const uint4*>(gKt + 24);
            vr0 = *reinterpret_cast<const uint4*>(gVt);
            vr1 = *reinterpret_cast<const uint4*>(gVt + 8);
            vr2 = *reinterpret_cast<const uint4*>(gVt + 16);
            vr3 = *reinterpret_cast<const uint4*>(gVt + 24);
        }

#pragma unroll
        for (int h2 = 0; h2 < 2; ++h2) {
            const int k0h = t * 128 + h2 * 64;
            if (k0h <= q0w + 31) {   // wave-uniform validity (per half)
                const u16* Kb = SM + h2 * 64 * 72;
                const u16* Vb = SM + 9216 + h2 * 64;
                // ---- S' = (C2 Q) K^T via mfma (swapped) ----
                f32x16 st0 = {}, st1 = {};
#pragma unroll
                for (int s = 0; s < 4; ++s) {
                    short8v kfa = *reinterpret_cast<const short8v*>(&Kb[q31 * 72 + s * 16 + hi * 8]);
                    short8v kfb = *reinterpret_cast<const short8v*>(&Kb[(q31 + 32) * 72 + s * 16 + hi * 8]);
                    short8v qs = (s == 0) ? qf0 : (s == 1) ? qf1 : (s == 2) ? qf2 : qf3;
                    st0 = __builtin_amdgcn_mfma_f32_32x32x16_bf16(kfa, qs, st0, 0, 0, 0);
                    st1 = __builtin_amdgcn_mfma_f32_32x32x16_bf16(kfb, qs, st1, 0, 0, 0);
                }
                // ---- causal mask + exp2 ----
                const bool diag = (k0h + 63 > q0w);
                float s0[16], s1[16];
                float rs = 0.f;
#pragma unroll
                for (int r = 0; r < 16; ++r) {
                    int krel = (r & 3) + 8 * (r >> 2) + 4 * hi;
                    float v0 = st0[r];
                    float v1 = st1[r];
                    if (diag) {
                        if (k0h + krel > qlane) v0 = -1e30f;
                        if (k0h + 32 + krel > qlane) v1 = -1e30f;
                    }
                    float p0 = exp2g(v0);
                    float p1 = exp2g(v1);
                    s0[r] = p0; s1[r] = p1;
                    rs += p0 + p1;
                }
                rs += __shfl_xor(rs, 32);
                l_run += rs;

                // ---- P -> bf16 B-frags via cvt_pk + permlane32_swap ----
                short8v pf0, pf1, pf2, pf3;
#define MKFRAG(dst, P, rb)                                                  \
                {                                                           \
                    unsigned int a_ = pk2(P[rb + 0], P[rb + 1]);            \
                    unsigned int b_ = pk2(P[rb + 4], P[rb + 5]);            \
                    unsigned int c_ = pk2(P[rb + 2], P[rb + 3]);            \
                    unsigned int d_ = pk2(P[rb + 6], P[rb + 7]);            \
                    plswap(a_, b_);                                         \
                    plswap(c_, d_);                                         \
                    union { unsigned int u[4]; short8v s; } uf_;            \
                    uf_.u[0] = a_; uf_.u[1] = c_; uf_.u[2] = b_; uf_.u[3] = d_; \
                    dst = uf_.s;                                            \
                }
                MKFRAG(pf0, s0, 0)
                MKFRAG(pf1, s0, 8)
                MKFRAG(pf2, s1, 0)
                MKFRAG(pf3, s1, 8)
#undef MKFRAG
                // ---- O^T += V^T P^T ----
#pragma unroll
                for (int s = 0; s < 4; ++s) {
                    short8v vfa = *reinterpret_cast<const short8v*>(&Vb[q31 * 136 + s * 16 + hi * 8]);
                    short8v vfb = *reinterpret_cast<const short8v*>(&Vb[(q31 + 32) * 136 + s * 16 + hi * 8]);
                    short8v ps = (s == 0) ? pf0 : (s == 1) ? pf1 : (s == 2) ? pf2 : pf3;
                    acc0 = __builtin_amdgcn_mfma_f32_32x32x16_bf16(vfa, ps, acc0, 0, 0, 0);
                    acc1 = __builtin_amdgcn_mfma_f32_32x32x16_bf16(vfb, ps, acc1, 0, 0, 0);
                }
            }
        }

        __syncthreads();   // all waves done reading step t
        if (pre) {
            *reinterpret_cast<uint4*>(&SM[soffK]) = kr0;
            *reinterpret_cast<uint4*>(&SM[soffK + 8]) = kr1;
            *reinterpret_cast<uint4*>(&SM[soffK + 16]) = kr2;
            *reinterpret_cast<uint4*>(&SM[soffK + 24]) = kr3;
            *reinterpret_cast<uint4*>(&SM[soffV]) = vr0;
            *reinterpret_cast<uint4*>(&SM[soffV + 8]) = vr1;
            *reinterpret_cast<uint4*>(&SM[soffV + 16]) = vr2;
            *reinterpret_cast<uint4*>(&SM[soffV + 24]) = vr3;
        }
        __syncthreads();   // step t+1 data visible
    }

    // ---- store O: LDS transpose -> coalesced 16B stores ----
    const float inv = 1.f / l_run;
    unsigned int* Od2 = reinterpret_cast<unsigned int*>(SM);
    const int qrow = w * 32 + q31;
#pragma unroll
    for (int r = 0; r < 16; r += 2) {
        int d0 = (r & 3) + 8 * (r >> 2) + 4 * hi;   // even
        Od2[qrow * 36 + (d0 >> 1)] = pk2(acc0[r] * inv, acc0[r + 1] * inv);
        Od2[qrow * 36 + ((32 + d0) >> 1)] = pk2(acc1[r] * inv, acc1[r + 1] * inv);
    }
    __syncthreads();
    {
        const int row = w * 32 + (l >> 1);
        const int dh = (l & 1) * 32;
        const u16* src = SM + row * 72 + dh;
        u16* dst = y + (tok0 + chunk * 128 + row) * Cc + h * 64 + dh;
#pragma unroll
        for (int k2 = 0; k2 < 4; ++k2)
            *reinterpret_cast<uint4*>(dst + k2 * 8) =
                *reinterpret_cast<const uint4*>(src + k2 * 8);
    }
}

extern "C" void kernel_launch(void* const* d_in, const int* in_sizes, int n_in,
                              void* d_out, int out_size, void* d_ws, size_t ws_size,
                              hipStream_t stream) {
    const float* x    = (const float*)d_in[0];
    const float* Wqkv = (const float*)d_in[1];
    const float* Wout = (const float*)d_in[2];
    float* out = (float*)d_out;

    // ws layout (bytes):
    //   qk   bf16 [8192][2048]            @ 0        (33,554,432)
    //   vT   bf16 [4][1024 d][2048 t]     @ 33554432 (16,777,216)
    //   x_bf bf16 [8192][1024] (later y)  @ 50331648 (16,777,216)
    //   WqkvT bf16 [3072][1024]           @ 67108864 ( 6,291,456)
    //   WoutT bf16 [1024][1024]           @ 73400320 ( 2,097,152)
    char* ws = (char*)d_ws;
    u16* qk    = (u16*)(ws);
    u16* vT    = (u16*)(ws + 33554432);
    u16* xbf   = (u16*)(ws + 50331648);  // aliased as y after GEMM1
    u16* WqkvT = (u16*)(ws + 67108864);
    u16* WoutT = (u16*)(ws + 73400320);

    prep<<<8192 + 3072 + 1024, 256, 0, stream>>>(x, xbf, Wqkv, WqkvT, Wout, WoutT);

    gemm256_qkv<<<dim3(Mm / 256, C3 / 256), 512, 0, stream>>>(xbf, WqkvT, qk, vT, Cc);

    u16* ybf = xbf;
    attn_mfma<<<1024, 256, 0, stream>>>(qk, vT, ybf);

    gemm_mfma<1><<<dim3(Mm / 128, Cc / 128), 256, 0, stream>>>(ybf, WoutT, out, Mm, Cc, Cc);
}

// Round 23
// 176.347 us; speedup vs baseline: 1.0437x; 1.0437x over previous
//
#include <hip/hip_runtime.h>
#include <hip/hip_bf16.h>

typedef unsigned short u16;
typedef __attribute__((ext_vector_type(8))) short short8v;   // 8 bf16 = 4 VGPR
typedef __attribute__((ext_vector_type(4))) float f32x4;     // mfma 16x16 acc
typedef __attribute__((ext_vector_type(16))) float f32x16;   // mfma 32x32 acc

#define Bb 4
#define Tt 2048
#define Cc 1024
#define Hh 16
#define C3 3072
#define Mm 8192

__device__ __forceinline__ u16 f2bf(float f) {
    union { __hip_bfloat16 h; u16 u; } r;
    r.h = __float2bfloat16(f);
    return r.u;
}
__device__ __forceinline__ unsigned int pk2(float a, float b) {
    union { __hip_bfloat162 h; unsigned int u; } r;
    r.h.x = __float2bfloat16(a);
    r.h.y = __float2bfloat16(b);
    return r.u;
}
__device__ __forceinline__ float exp2g(float x) {
#if __has_builtin(__builtin_amdgcn_exp2f)
    return __builtin_amdgcn_exp2f(x);
#else
    return exp2f(x);
#endif
}
__device__ __forceinline__ void plswap(unsigned int& a, unsigned int& b) {
#if __has_builtin(__builtin_amdgcn_permlane32_swap)
    typedef __attribute__((ext_vector_type(2))) unsigned int uint2v;
    uint2v r = __builtin_amdgcn_permlane32_swap(a, b, false, false);
    a = r.x; b = r.y;
#else
    asm volatile("v_permlane32_swap_b32 %0, %1" : "+v"(a), "+v"(b));
#endif
}
// global -> LDS direct (16B/lane). LDS dest: wave-uniform base + lane*16.
__device__ __forceinline__ void gload16(const void* g, void* l) {
    __builtin_amdgcn_global_load_lds(
        (const __attribute__((address_space(1))) unsigned int*)g,
        (__attribute__((address_space(3))) unsigned int*)l, 16, 0, 0);
}
// scale 8 bf16 by constant (unpack -> mul -> repack), used once per block
__device__ __forceinline__ short8v scale8(short8v v, float s) {
    union { short8v sv; unsigned int u[4]; } in, out;
    in.sv = v;
#pragma unroll
    for (int i = 0; i < 4; ++i) {
        float lo = __uint_as_float(in.u[i] << 16);
        float hi = __uint_as_float(in.u[i] & 0xffff0000u);
        out.u[i] = pk2(lo * s, hi * s);
    }
    return out.sv;
}

// ---------- merged preprocessing: cvt_x + wtrans(Wqkv) + wtrans(Wout) ----------
__global__ __launch_bounds__(256) void prep(const float* __restrict__ x,
                                            u16* __restrict__ xbf,
                                            const float* __restrict__ Wqkv,
                                            u16* __restrict__ WqkvT,
                                            const float* __restrict__ Wout,
                                            u16* __restrict__ WoutT) {
    __shared__ float t[32][33];
    const int blk = blockIdx.x;
    if (blk < 8192) {
        int i = blk * 256 + threadIdx.x;
        float4 v = reinterpret_cast<const float4*>(x)[i];
        ushort4 o;
        o.x = f2bf(v.x); o.y = f2bf(v.y); o.z = f2bf(v.z); o.w = f2bf(v.w);
        reinterpret_cast<ushort4*>(xbf)[i] = o;
        return;
    }
    const float* in;
    u16* out;
    int R, Ccols, bx, by;
    if (blk < 8192 + 3072) {
        const int idx = blk - 8192;
        in = Wqkv; out = WqkvT; R = Cc; Ccols = C3;
        bx = idx % 96; by = idx / 96;
    } else {
        const int idx = blk - (8192 + 3072);
        in = Wout; out = WoutT; R = Cc; Ccols = Cc;
        bx = idx & 31; by = idx >> 5;
    }
    const int tx = threadIdx.x & 31, ty = threadIdx.x >> 5;  // 32x8
    const int c = bx * 32 + tx;
#pragma unroll
    for (int j = 0; j < 4; ++j) {
        int r = by * 32 + ty + j * 8;
        t[ty + j * 8][tx] = in[(size_t)r * Ccols + c];
    }
    __syncthreads();
#pragma unroll
    for (int j = 0; j < 4; ++j) {
        int orow = bx * 32 + ty + j * 8;
        int oc   = by * 32 + tx;
        out[(size_t)orow * R + oc] = f2bf(t[tx][ty + j * 8]);
    }
}

// ---------- 128x128 MFMA GEMM (m97 structure) — GEMM2, scalar epilogue ----------
template <int OUTF32>
__global__ __launch_bounds__(256) void gemm_mfma(const u16* __restrict__ A,
                                                 const u16* __restrict__ BT,
                                                 void* __restrict__ C0,
                                                 int M, int N, int K) {
    __shared__ u16 As[128 * 32];
    __shared__ u16 Bs[128 * 32];
    const int tid = threadIdx.x;
    const int w = tid >> 6, l = tid & 63;
    const int wr = w >> 1, wc = w & 1;
    const int g = l >> 4, q = l & 15;
    const int bm = blockIdx.x * 128, bn = blockIdx.y * 128;
    const int lrow = l >> 2;
    const int lcol = (l & 3) * 8;

    f32x4 acc[4][4] = {};
    const u16* Ap = A + (size_t)(bm + w * 32 + lrow) * K + lcol;
    const u16* Bp = BT + (size_t)(bn + w * 32 + lrow) * K + lcol;

    for (int k0 = 0; k0 < K; k0 += 32) {
        gload16(Ap + k0, &As[(w * 32) * 32]);
        gload16(Ap + (size_t)16 * K + k0, &As[(w * 32 + 16) * 32]);
        gload16(Bp + k0, &Bs[(w * 32) * 32]);
        gload16(Bp + (size_t)16 * K + k0, &Bs[(w * 32 + 16) * 32]);
        __syncthreads();
        short8v af[4], bf[4];
#pragma unroll
        for (int m = 0; m < 4; ++m)
            af[m] = *reinterpret_cast<const short8v*>(&As[(wr * 64 + m * 16 + q) * 32 + g * 8]);
#pragma unroll
        for (int n = 0; n < 4; ++n)
            bf[n] = *reinterpret_cast<const short8v*>(&Bs[(wc * 64 + n * 16 + q) * 32 + g * 8]);
#pragma unroll
        for (int m = 0; m < 4; ++m)
#pragma unroll
            for (int n = 0; n < 4; ++n)
                acc[m][n] = __builtin_amdgcn_mfma_f32_16x16x32_bf16(af[m], bf[n], acc[m][n], 0, 0, 0);
        __syncthreads();
    }

#pragma unroll
    for (int m = 0; m < 4; ++m)
#pragma unroll
        for (int n = 0; n < 4; ++n)
#pragma unroll
            for (int r = 0; r < 4; ++r) {
                int row = bm + wr * 64 + m * 16 + g * 4 + r;
                int col = bn + wc * 64 + n * 16 + q;
                if (OUTF32)
                    reinterpret_cast<float*>(C0)[(size_t)row * N + col] = acc[m][n][r];
                else
                    reinterpret_cast<u16*>(C0)[(size_t)row * N + col] = f2bf(acc[m][n][r]);
            }
}

// ---------- 256x256 BK=64 8-wave GEMM, 4-sub-phase interleave (r18 verified) ----
__global__ __launch_bounds__(512, 2) void gemm256_qkv(const u16* __restrict__ A,
                                                      const u16* __restrict__ BT,
                                                      u16* __restrict__ qkOut,
                                                      u16* __restrict__ vTOut,
                                                      int K) {
    __shared__ u16 SM[65536];   // 128 KiB
    const int tid = threadIdx.x;
    const int wv = tid >> 6, L = tid & 63;
    const int wm = wv >> 2, wn = wv & 3;        // 2 x 4 waves
    const int q = L & 15, g = L >> 4;
    const int bm = blockIdx.x * 256, bn = blockIdx.y * 256;
    const int nK = K >> 6;

    char* smB = (char*)SM;
    const int srow = wv * 16 + (L >> 3);
    const int scol = ((L & 7) ^ ((L >> 3) & 7)) * 8;   // u16 (inverse swizzle on src)
    const u16* Asrc = A + (size_t)(bm + srow) * K + scol;
    const u16* Bsrc = BT + (size_t)(bn + srow) * K + scol;

#define STG2(src, ldsByte)                                                \
    { gload16((src), smB + (ldsByte) + wv * 2048);                        \
      gload16((src) + 8 * (size_t)K, smB + (ldsByte) + wv * 2048 + 1024); }

    // prologue: K0 {A0,A1,B0,B1} -> buf0 ; K1 {A0,A1,B0} -> buf1
    STG2(Asrc, 0)
    STG2(Asrc + 128 * (size_t)K, 16384)
    STG2(Bsrc, 32768)
    STG2(Bsrc + 128 * (size_t)K, 49152)
    STG2(Asrc + 64, 65536)
    STG2(Asrc + 128 * (size_t)K + 64, 65536 + 16384)
    STG2(Bsrc + 64, 65536 + 32768)

    const int rA = (wm * 128 + q) * 64;
    const int rB = 16384 + (wn * 64 + q) * 64;
    const int s0 = (g ^ (q & 7)) * 8;           // ks=0 slot
    const int s1 = ((4 + g) ^ (q & 7)) * 8;     // ks=1 slot

    f32x4 acc[8][4] = {};

#define LDA2(dst, mf)                                                                   \
    dst[0] = *reinterpret_cast<const short8v*>(&SM[bufU + rA + mf * 1024 + s0]);        \
    dst[1] = *reinterpret_cast<const short8v*>(&SM[bufU + rA + mf * 1024 + s1]);
#define LDB2(nf)                                                                        \
    Bf##nf[0] = *reinterpret_cast<const short8v*>(&SM[bufU + rB + nf * 1024 + s0]);     \
    Bf##nf[1] = *reinterpret_cast<const short8v*>(&SM[bufU + rB + nf * 1024 + s1]);
#define MMA2(Aa, nf, ia)                                                                       \
    acc[ia][nf] = __builtin_amdgcn_mfma_f32_16x16x32_bf16(Aa[0], Bf##nf[0], acc[ia][nf], 0, 0, 0); \
    acc[ia][nf] = __builtin_amdgcn_mfma_f32_16x16x32_bf16(Aa[1], Bf##nf[1], acc[ia][nf], 0, 0, 0);
#define MBLK2(Aa, Ab, ia, ib)                                             \
    __builtin_amdgcn_s_setprio(1);                                        \
    MMA2(Aa, 0, ia) MMA2(Aa, 1, ia) MMA2(Aa, 2, ia) MMA2(Aa, 3, ia)       \
    MMA2(Ab, 0, ib) MMA2(Ab, 1, ib) MMA2(Ab, 2, ib) MMA2(Ab, 3, ib)       \
    __builtin_amdgcn_s_setprio(0);

    for (int t = 0; t < nK; ++t) {
        const int bufU = (t & 1) * 32768;
        const int curB = (t & 1) * 65536;
        const int nxtB = ((t + 1) & 1) * 65536;
        if (t == nK - 1) { asm volatile("s_waitcnt vmcnt(0)" ::: "memory"); }
        else             { asm volatile("s_waitcnt vmcnt(6)" ::: "memory"); }
        __builtin_amdgcn_s_barrier();
        __builtin_amdgcn_sched_barrier(0);

        short8v Bf0[2], Bf1[2], Bf2[2], Bf3[2];
        LDB2(0) LDB2(1) LDB2(2) LDB2(3)
        short8v Af0[2], Af1[2];
        LDA2(Af0, 0) LDA2(Af1, 1)
        if (t + 1 < nK) STG2(Bsrc + 128 * (size_t)K + (t + 1) * 64, nxtB + 49152)
        __builtin_amdgcn_sched_barrier(0);
        MBLK2(Af0, Af1, 0, 1)
        __builtin_amdgcn_sched_barrier(0);

        short8v Af2[2], Af3[2];
        LDA2(Af2, 2) LDA2(Af3, 3)
        __builtin_amdgcn_sched_barrier(0);
        MBLK2(Af2, Af3, 2, 3)
        __builtin_amdgcn_sched_barrier(0);

        short8v Af4[2], Af5[2];
        LDA2(Af4, 4) LDA2(Af5, 5)
        __builtin_amdgcn_sched_barrier(0);
        MBLK2(Af4, Af5, 4, 5)
        __builtin_amdgcn_sched_barrier(0);

        short8v Af6[2], Af7[2];
        LDA2(Af6, 6) LDA2(Af7, 7)
        asm volatile("s_waitcnt lgkmcnt(0)" ::: "memory");
        __builtin_amdgcn_sched_barrier(0);
        __builtin_amdgcn_s_barrier();
        if (t + 2 < nK) {
            STG2(Asrc + (t + 2) * 64, curB)
            STG2(Asrc + 128 * (size_t)K + (t + 2) * 64, curB + 16384)
            STG2(Bsrc + (t + 2) * 64, curB + 32768)
        }
        __builtin_amdgcn_sched_barrier(0);
        MBLK2(Af6, Af7, 6, 7)
    }
#undef MMA2
#undef MBLK2
#undef LDA2
#undef LDB2
#undef STG2

    // ---- epilogue ----
    __builtin_amdgcn_s_barrier();   // all waves past final LDS reads
    if (bn < 2048) {
        char* smb2 = (char*)SM;
#pragma unroll
        for (int mf = 0; mf < 8; ++mf) {
            const int row = wm * 128 + mf * 16 + g * 4;
#pragma unroll
            for (int nf = 0; nf < 4; ++nf) {
                const int col = wn * 64 + nf * 16 + q;
#pragma unroll
                for (int rr = 0; rr < 4; ++rr) {
                    const int r2 = row + rr;
                    *(u16*)(smb2 + r2 * 512 + ((((col >> 3) ^ (r2 & 7))) << 4) + (col & 7) * 2)
                        = f2bf(acc[mf][nf][rr]);
                }
            }
        }
        __syncthreads();
        const int erow = tid >> 1;
        const int ebase = (tid & 1) * 16;
        u16* orow = qkOut + (size_t)(bm + erow) * 2048 + bn;
#pragma unroll
        for (int j = 0; j < 16; ++j) {
            const int s = ebase + j;
            uint4 v = *(const uint4*)(smb2 + erow * 512 + ((s ^ (erow & 7)) << 4));
            *reinterpret_cast<uint4*>(orow + s * 8) = v;
        }
    } else {
        const int colb = bn - 2048 + wn * 64;
        const int bI = bm >> 11;
        const int tIb = (bm & 2047) + wm * 128 + g * 4;
#pragma unroll
        for (int mf = 0; mf < 8; ++mf)
#pragma unroll
            for (int nf = 0; nf < 4; ++nf) {
                const int col = colb + nf * 16 + q;
                uint2 pv;
                pv.x = pk2(acc[mf][nf][0], acc[mf][nf][1]);
                pv.y = pk2(acc[mf][nf][2], acc[mf][nf][3]);
                *reinterpret_cast<uint2*>(
                    &vTOut[((size_t)bI * 1024 + col) * 2048 + tIb + mf * 16]) = pv;
            }
    }
}

// ---------- MFMA flash attention (causal), static-max softmax (r21 verified) ----
// 1024 blocks, one 128-q chunk each, LPT order. Single-buffered K+V LDS.
// Q pre-scaled by C2 (bf16) -> per-element softmax work = one exp2 only.
__global__ __launch_bounds__(256) void attn_mfma(const u16* __restrict__ qk,
                                                 const u16* __restrict__ vT,
                                                 u16* __restrict__ y) {
    __shared__ u16 SM[9216];    // 18,432 B: K [64][72] | V^T [64][72]
    const int tid = threadIdx.x;
    const int w = tid >> 6, l = tid & 63;
    const int q31 = l & 31, hi = l >> 5;
    const int bid = blockIdx.x;
    const int bh = bid & 63;
    const int chunk = 15 - (bid >> 6);        // LPT: big chunks first
    const int b = bh >> 4, h = bh & 15;
    const size_t tok0 = (size_t)b * Tt;

    const float C2 = 0.18033688011112042f;   // 0.125 * log2(e), folded into Q

    const int srow = tid >> 2;
    const int sseg = (tid & 3) * 16;
    const int soff = srow * 72 + sseg;
    const u16* gK = qk + (tok0 + srow) * 2048 + 1024 + h * 64 + sseg;
    const u16* gV = vT + ((size_t)b * 1024 + h * 64 + srow) * 2048 + sseg;

    const int nsteps = 2 * (chunk + 1);
    const int q0w = chunk * 128 + w * 32;
    const int qlane = q0w + q31;

    short8v qf0, qf1, qf2, qf3;
    {
        const u16* qp = qk + (tok0 + qlane) * 2048 + h * 64 + hi * 8;
        qf0 = scale8(*reinterpret_cast<const short8v*>(qp), C2);
        qf1 = scale8(*reinterpret_cast<const short8v*>(qp + 16), C2);
        qf2 = scale8(*reinterpret_cast<const short8v*>(qp + 32), C2);
        qf3 = scale8(*reinterpret_cast<const short8v*>(qp + 48), C2);
    }

    f32x16 acc0 = {}, acc1 = {};
    float l_run = 0.f;

    {   // prologue: stage tile 0
        uint4 ka = *reinterpret_cast<const uint4*>(gK);
        uint4 kb = *reinterpret_cast<const uint4*>(gK + 8);
        uint4 va = *reinterpret_cast<const uint4*>(gV);
        uint4 vb = *reinterpret_cast<const uint4*>(gV + 8);
        *reinterpret_cast<uint4*>(&SM[soff]) = ka;
        *reinterpret_cast<uint4*>(&SM[soff + 8]) = kb;
        *reinterpret_cast<uint4*>(&SM[4608 + soff]) = va;
        *reinterpret_cast<uint4*>(&SM[4608 + soff + 8]) = vb;
    }
    __syncthreads();

    for (int t = 0; t < nsteps; ++t) {
        const int k0 = t * 64;
        const bool pre = (t + 1 < nsteps);
        uint4 ka = {}, kb = {}, va = {}, vb = {};
        if (pre) {
            const u16* gKt = gK + (size_t)(t + 1) * 64 * 2048;
            const u16* gVt = gV + (t + 1) * 64;
            ka = *reinterpret_cast<const uint4*>(gKt);
            kb = *reinterpret_cast<const uint4*>(gKt + 8);
            va = *reinterpret_cast<const uint4*>(gVt);
            vb = *reinterpret_cast<const uint4*>(gVt + 8);
        }

        if (k0 <= q0w + 31) {
            const u16* Kb = SM;
            const u16* Vb = SM + 4608;
            // ---- S' = (C2 Q) K^T via mfma (swapped) ----
            f32x16 st0 = {}, st1 = {};
#pragma unroll
            for (int s = 0; s < 4; ++s) {
                short8v kfa = *reinterpret_cast<const short8v*>(&Kb[q31 * 72 + s * 16 + hi * 8]);
                short8v kfb = *reinterpret_cast<const short8v*>(&Kb[(q31 + 32) * 72 + s * 16 + hi * 8]);
                short8v qs = (s == 0) ? qf0 : (s == 1) ? qf1 : (s == 2) ? qf2 : qf3;
                st0 = __builtin_amdgcn_mfma_f32_32x32x16_bf16(kfa, qs, st0, 0, 0, 0);
                st1 = __builtin_amdgcn_mfma_f32_32x32x16_bf16(kfb, qs, st1, 0, 0, 0);
            }
            // ---- causal mask + exp2 ----
            const bool diag = (k0 + 63 > q0w);
            float s0[16], s1[16];
            float rs = 0.f;
#pragma unroll
            for (int r = 0; r < 16; ++r) {
                int krel = (r & 3) + 8 * (r >> 2) + 4 * hi;
                float v0 = st0[r];
                float v1 = st1[r];
                if (diag) {
                    if (k0 + krel > qlane) v0 = -1e30f;
                    if (k0 + 32 + krel > qlane) v1 = -1e30f;
                }
                float p0 = exp2g(v0);
                float p1 = exp2g(v1);
                s0[r] = p0; s1[r] = p1;
                rs += p0 + p1;
            }
            rs += __shfl_xor(rs, 32);
            l_run += rs;

            // ---- P -> bf16 B-frags via cvt_pk + permlane32_swap ----
            short8v pf0, pf1, pf2, pf3;
#define MKFRAG(dst, P, rb)                                                  \
            {                                                               \
                unsigned int a_ = pk2(P[rb + 0], P[rb + 1]);                \
                unsigned int b_ = pk2(P[rb + 4], P[rb + 5]);                \
                unsigned int c_ = pk2(P[rb + 2], P[rb + 3]);                \
                unsigned int d_ = pk2(P[rb + 6], P[rb + 7]);                \
                plswap(a_, b_);                                             \
                plswap(c_, d_);                                             \
                union { unsigned int u[4]; short8v s; } uf_;                \
                uf_.u[0] = a_; uf_.u[1] = c_; uf_.u[2] = b_; uf_.u[3] = d_; \
                dst = uf_.s;                                                \
            }
            MKFRAG(pf0, s0, 0)
            MKFRAG(pf1, s0, 8)
            MKFRAG(pf2, s1, 0)
            MKFRAG(pf3, s1, 8)
#undef MKFRAG
            // ---- O^T += V^T P^T ----
#pragma unroll
            for (int s = 0; s < 4; ++s) {
                short8v vfa = *reinterpret_cast<const short8v*>(&Vb[q31 * 72 + s * 16 + hi * 8]);
                short8v vfb = *reinterpret_cast<const short8v*>(&Vb[(q31 + 32) * 72 + s * 16 + hi * 8]);
                short8v ps = (s == 0) ? pf0 : (s == 1) ? pf1 : (s == 2) ? pf2 : pf3;
                acc0 = __builtin_amdgcn_mfma_f32_32x32x16_bf16(vfa, ps, acc0, 0, 0, 0);
                acc1 = __builtin_amdgcn_mfma_f32_32x32x16_bf16(vfb, ps, acc1, 0, 0, 0);
            }
        }

        __syncthreads();   // all waves done reading step t
        if (pre) {
            *reinterpret_cast<uint4*>(&SM[soff]) = ka;
            *reinterpret_cast<uint4*>(&SM[soff + 8]) = kb;
            *reinterpret_cast<uint4*>(&SM[4608 + soff]) = va;
            *reinterpret_cast<uint4*>(&SM[4608 + soff + 8]) = vb;
        }
        __syncthreads();   // step t+1 data visible
    }

    // ---- store O: LDS transpose -> coalesced 16B stores ----
    const float inv = 1.f / l_run;
    unsigned int* Od2 = reinterpret_cast<unsigned int*>(SM);
    const int qrow = w * 32 + q31;
#pragma unroll
    for (int r = 0; r < 16; r += 2) {
        int d0 = (r & 3) + 8 * (r >> 2) + 4 * hi;   // even
        Od2[qrow * 36 + (d0 >> 1)] = pk2(acc0[r] * inv, acc0[r + 1] * inv);
        Od2[qrow * 36 + ((32 + d0) >> 1)] = pk2(acc1[r] * inv, acc1[r + 1] * inv);
    }
    __syncthreads();
    {
        const int row = w * 32 + (l >> 1);
        const int dh = (l & 1) * 32;
        const u16* src = SM + row * 72 + dh;
        u16* dst = y + (tok0 + chunk * 128 + row) * Cc + h * 64 + dh;
#pragma unroll
        for (int k2 = 0; k2 < 4; ++k2)
            *reinterpret_cast<uint4*>(dst + k2 * 8) =
                *reinterpret_cast<const uint4*>(src + k2 * 8);
    }
}

extern "C" void kernel_launch(void* const* d_in, const int* in_sizes, int n_in,
                              void* d_out, int out_size, void* d_ws, size_t ws_size,
                              hipStream_t stream) {
    const float* x    = (const float*)d_in[0];
    const float* Wqkv = (const float*)d_in[1];
    const float* Wout = (const float*)d_in[2];
    float* out = (float*)d_out;

    // ws layout (bytes):
    //   qk   bf16 [8192][2048]            @ 0        (33,554,432)
    //   vT   bf16 [4][1024 d][2048 t]     @ 33554432 (16,777,216)
    //   x_bf bf16 [8192][1024] (later y)  @ 50331648 (16,777,216)
    //   WqkvT bf16 [3072][1024]           @ 67108864 ( 6,291,456)
    //   WoutT bf16 [1024][1024]           @ 73400320 ( 2,097,152)
    char* ws = (char*)d_ws;
    u16* qk    = (u16*)(ws);
    u16* vT    = (u16*)(ws + 33554432);
    u16* xbf   = (u16*)(ws + 50331648);  // aliased as y after GEMM1
    u16* WqkvT = (u16*)(ws + 67108864);
    u16* WoutT = (u16*)(ws + 73400320);

    prep<<<8192 + 3072 + 1024, 256, 0, stream>>>(x, xbf, Wqkv, WqkvT, Wout, WoutT);

    gemm256_qkv<<<dim3(Mm / 256, C3 / 256), 512, 0, stream>>>(xbf, WqkvT, qk, vT, Cc);

    u16* ybf = xbf;
    attn_mfma<<<1024, 256, 0, stream>>>(qk, vT, ybf);

    gemm_mfma<1><<<dim3(Mm / 128, Cc / 128), 256, 0, stream>>>(ybf, WoutT, out, Mm, Cc, Cc);
}

// Round 24
// 175.948 us; speedup vs baseline: 1.0461x; 1.0023x over previous
//
#include <hip/hip_runtime.h>
#include <hip/hip_bf16.h>

typedef unsigned short u16;
typedef __attribute__((ext_vector_type(8))) short short8v;   // 8 bf16 = 4 VGPR
typedef __attribute__((ext_vector_type(4))) float f32x4;     // mfma 16x16 acc
typedef __attribute__((ext_vector_type(16))) float f32x16;   // mfma 32x32 acc

#define Bb 4
#define Tt 2048
#define Cc 1024
#define Hh 16
#define C3 3072
#define Mm 8192

__device__ __forceinline__ u16 f2bf(float f) {
    union { __hip_bfloat16 h; u16 u; } r;
    r.h = __float2bfloat16(f);
    return r.u;
}
__device__ __forceinline__ unsigned int pk2(float a, float b) {
    union { __hip_bfloat162 h; unsigned int u; } r;
    r.h.x = __float2bfloat16(a);
    r.h.y = __float2bfloat16(b);
    return r.u;
}
__device__ __forceinline__ float exp2g(float x) {
#if __has_builtin(__builtin_amdgcn_exp2f)
    return __builtin_amdgcn_exp2f(x);
#else
    return exp2f(x);
#endif
}
__device__ __forceinline__ void plswap(unsigned int& a, unsigned int& b) {
#if __has_builtin(__builtin_amdgcn_permlane32_swap)
    typedef __attribute__((ext_vector_type(2))) unsigned int uint2v;
    uint2v r = __builtin_amdgcn_permlane32_swap(a, b, false, false);
    a = r.x; b = r.y;
#else
    asm volatile("v_permlane32_swap_b32 %0, %1" : "+v"(a), "+v"(b));
#endif
}
// global -> LDS direct (16B/lane). LDS dest: wave-uniform base + lane*16.
__device__ __forceinline__ void gload16(const void* g, void* l) {
    __builtin_amdgcn_global_load_lds(
        (const __attribute__((address_space(1))) unsigned int*)g,
        (__attribute__((address_space(3))) unsigned int*)l, 16, 0, 0);
}
// scale 8 bf16 by constant (unpack -> mul -> repack), used once per block
__device__ __forceinline__ short8v scale8(short8v v, float s) {
    union { short8v sv; unsigned int u[4]; } in, out;
    in.sv = v;
#pragma unroll
    for (int i = 0; i < 4; ++i) {
        float lo = __uint_as_float(in.u[i] << 16);
        float hi = __uint_as_float(in.u[i] & 0xffff0000u);
        out.u[i] = pk2(lo * s, hi * s);
    }
    return out.sv;
}

// ---------- merged preprocessing: cvt_x + wtrans(Wqkv) + wtrans(Wout) ----------
__global__ __launch_bounds__(256) void prep(const float* __restrict__ x,
                                            u16* __restrict__ xbf,
                                            const float* __restrict__ Wqkv,
                                            u16* __restrict__ WqkvT,
                                            const float* __restrict__ Wout,
                                            u16* __restrict__ WoutT) {
    __shared__ float t[32][33];
    const int blk = blockIdx.x;
    if (blk < 8192) {
        int i = blk * 256 + threadIdx.x;
        float4 v = reinterpret_cast<const float4*>(x)[i];
        ushort4 o;
        o.x = f2bf(v.x); o.y = f2bf(v.y); o.z = f2bf(v.z); o.w = f2bf(v.w);
        reinterpret_cast<ushort4*>(xbf)[i] = o;
        return;
    }
    const float* in;
    u16* out;
    int R, Ccols, bx, by;
    if (blk < 8192 + 3072) {
        const int idx = blk - 8192;
        in = Wqkv; out = WqkvT; R = Cc; Ccols = C3;
        bx = idx % 96; by = idx / 96;
    } else {
        const int idx = blk - (8192 + 3072);
        in = Wout; out = WoutT; R = Cc; Ccols = Cc;
        bx = idx & 31; by = idx >> 5;
    }
    const int tx = threadIdx.x & 31, ty = threadIdx.x >> 5;  // 32x8
    const int c = bx * 32 + tx;
#pragma unroll
    for (int j = 0; j < 4; ++j) {
        int r = by * 32 + ty + j * 8;
        t[ty + j * 8][tx] = in[(size_t)r * Ccols + c];
    }
    __syncthreads();
#pragma unroll
    for (int j = 0; j < 4; ++j) {
        int orow = bx * 32 + ty + j * 8;
        int oc   = by * 32 + tx;
        out[(size_t)orow * R + oc] = f2bf(t[tx][ty + j * 8]);
    }
}

// ---------- 128x128 MFMA GEMM (m97 structure) — GEMM2, scalar epilogue ----------
template <int OUTF32>
__global__ __launch_bounds__(256) void gemm_mfma(const u16* __restrict__ A,
                                                 const u16* __restrict__ BT,
                                                 void* __restrict__ C0,
                                                 int M, int N, int K) {
    __shared__ u16 As[128 * 32];
    __shared__ u16 Bs[128 * 32];
    const int tid = threadIdx.x;
    const int w = tid >> 6, l = tid & 63;
    const int wr = w >> 1, wc = w & 1;
    const int g = l >> 4, q = l & 15;
    const int bm = blockIdx.x * 128, bn = blockIdx.y * 128;
    const int lrow = l >> 2;
    const int lcol = (l & 3) * 8;

    f32x4 acc[4][4] = {};
    const u16* Ap = A + (size_t)(bm + w * 32 + lrow) * K + lcol;
    const u16* Bp = BT + (size_t)(bn + w * 32 + lrow) * K + lcol;

    for (int k0 = 0; k0 < K; k0 += 32) {
        gload16(Ap + k0, &As[(w * 32) * 32]);
        gload16(Ap + (size_t)16 * K + k0, &As[(w * 32 + 16) * 32]);
        gload16(Bp + k0, &Bs[(w * 32) * 32]);
        gload16(Bp + (size_t)16 * K + k0, &Bs[(w * 32 + 16) * 32]);
        __syncthreads();
        short8v af[4], bf[4];
#pragma unroll
        for (int m = 0; m < 4; ++m)
            af[m] = *reinterpret_cast<const short8v*>(&As[(wr * 64 + m * 16 + q) * 32 + g * 8]);
#pragma unroll
        for (int n = 0; n < 4; ++n)
            bf[n] = *reinterpret_cast<const short8v*>(&Bs[(wc * 64 + n * 16 + q) * 32 + g * 8]);
#pragma unroll
        for (int m = 0; m < 4; ++m)
#pragma unroll
            for (int n = 0; n < 4; ++n)
                acc[m][n] = __builtin_amdgcn_mfma_f32_16x16x32_bf16(af[m], bf[n], acc[m][n], 0, 0, 0);
        __syncthreads();
    }

#pragma unroll
    for (int m = 0; m < 4; ++m)
#pragma unroll
        for (int n = 0; n < 4; ++n)
#pragma unroll
            for (int r = 0; r < 4; ++r) {
                int row = bm + wr * 64 + m * 16 + g * 4 + r;
                int col = bn + wc * 64 + n * 16 + q;
                if (OUTF32)
                    reinterpret_cast<float*>(C0)[(size_t)row * N + col] = acc[m][n][r];
                else
                    reinterpret_cast<u16*>(C0)[(size_t)row * N + col] = f2bf(acc[m][n][r]);
            }
}

// ---------- 256x256 BK=64 8-wave GEMM, 4-sub-phase interleave (r18 verified) ----
__global__ __launch_bounds__(512, 2) void gemm256_qkv(const u16* __restrict__ A,
                                                      const u16* __restrict__ BT,
                                                      u16* __restrict__ qkOut,
                                                      u16* __restrict__ vTOut,
                                                      int K) {
    __shared__ u16 SM[65536];   // 128 KiB
    const int tid = threadIdx.x;
    const int wv = tid >> 6, L = tid & 63;
    const int wm = wv >> 2, wn = wv & 3;        // 2 x 4 waves
    const int q = L & 15, g = L >> 4;
    const int bm = blockIdx.x * 256, bn = blockIdx.y * 256;
    const int nK = K >> 6;

    char* smB = (char*)SM;
    const int srow = wv * 16 + (L >> 3);
    const int scol = ((L & 7) ^ ((L >> 3) & 7)) * 8;   // u16 (inverse swizzle on src)
    const u16* Asrc = A + (size_t)(bm + srow) * K + scol;
    const u16* Bsrc = BT + (size_t)(bn + srow) * K + scol;

#define STG2(src, ldsByte)                                                \
    { gload16((src), smB + (ldsByte) + wv * 2048);                        \
      gload16((src) + 8 * (size_t)K, smB + (ldsByte) + wv * 2048 + 1024); }

    // prologue: K0 {A0,A1,B0,B1} -> buf0 ; K1 {A0,A1,B0} -> buf1
    STG2(Asrc, 0)
    STG2(Asrc + 128 * (size_t)K, 16384)
    STG2(Bsrc, 32768)
    STG2(Bsrc + 128 * (size_t)K, 49152)
    STG2(Asrc + 64, 65536)
    STG2(Asrc + 128 * (size_t)K + 64, 65536 + 16384)
    STG2(Bsrc + 64, 65536 + 32768)

    const int rA = (wm * 128 + q) * 64;
    const int rB = 16384 + (wn * 64 + q) * 64;
    const int s0 = (g ^ (q & 7)) * 8;           // ks=0 slot
    const int s1 = ((4 + g) ^ (q & 7)) * 8;     // ks=1 slot

    f32x4 acc[8][4] = {};

#define LDA2(dst, mf)                                                                   \
    dst[0] = *reinterpret_cast<const short8v*>(&SM[bufU + rA + mf * 1024 + s0]);        \
    dst[1] = *reinterpret_cast<const short8v*>(&SM[bufU + rA + mf * 1024 + s1]);
#define LDB2(nf)                                                                        \
    Bf##nf[0] = *reinterpret_cast<const short8v*>(&SM[bufU + rB + nf * 1024 + s0]);     \
    Bf##nf[1] = *reinterpret_cast<const short8v*>(&SM[bufU + rB + nf * 1024 + s1]);
#define MMA2(Aa, nf, ia)                                                                       \
    acc[ia][nf] = __builtin_amdgcn_mfma_f32_16x16x32_bf16(Aa[0], Bf##nf[0], acc[ia][nf], 0, 0, 0); \
    acc[ia][nf] = __builtin_amdgcn_mfma_f32_16x16x32_bf16(Aa[1], Bf##nf[1], acc[ia][nf], 0, 0, 0);
#define MBLK2(Aa, Ab, ia, ib)                                             \
    __builtin_amdgcn_s_setprio(1);                                        \
    MMA2(Aa, 0, ia) MMA2(Aa, 1, ia) MMA2(Aa, 2, ia) MMA2(Aa, 3, ia)       \
    MMA2(Ab, 0, ib) MMA2(Ab, 1, ib) MMA2(Ab, 2, ib) MMA2(Ab, 3, ib)       \
    __builtin_amdgcn_s_setprio(0);

    for (int t = 0; t < nK; ++t) {
        const int bufU = (t & 1) * 32768;
        const int curB = (t & 1) * 65536;
        const int nxtB = ((t + 1) & 1) * 65536;
        if (t == nK - 1) { asm volatile("s_waitcnt vmcnt(0)" ::: "memory"); }
        else             { asm volatile("s_waitcnt vmcnt(6)" ::: "memory"); }
        __builtin_amdgcn_s_barrier();
        __builtin_amdgcn_sched_barrier(0);

        short8v Bf0[2], Bf1[2], Bf2[2], Bf3[2];
        LDB2(0) LDB2(1) LDB2(2) LDB2(3)
        short8v Af0[2], Af1[2];
        LDA2(Af0, 0) LDA2(Af1, 1)
        if (t + 1 < nK) STG2(Bsrc + 128 * (size_t)K + (t + 1) * 64, nxtB + 49152)
        __builtin_amdgcn_sched_barrier(0);
        MBLK2(Af0, Af1, 0, 1)
        __builtin_amdgcn_sched_barrier(0);

        short8v Af2[2], Af3[2];
        LDA2(Af2, 2) LDA2(Af3, 3)
        __builtin_amdgcn_sched_barrier(0);
        MBLK2(Af2, Af3, 2, 3)
        __builtin_amdgcn_sched_barrier(0);

        short8v Af4[2], Af5[2];
        LDA2(Af4, 4) LDA2(Af5, 5)
        __builtin_amdgcn_sched_barrier(0);
        MBLK2(Af4, Af5, 4, 5)
        __builtin_amdgcn_sched_barrier(0);

        short8v Af6[2], Af7[2];
        LDA2(Af6, 6) LDA2(Af7, 7)
        asm volatile("s_waitcnt lgkmcnt(0)" ::: "memory");
        __builtin_amdgcn_sched_barrier(0);
        __builtin_amdgcn_s_barrier();
        if (t + 2 < nK) {
            STG2(Asrc + (t + 2) * 64, curB)
            STG2(Asrc + 128 * (size_t)K + (t + 2) * 64, curB + 16384)
            STG2(Bsrc + (t + 2) * 64, curB + 32768)
        }
        __builtin_amdgcn_sched_barrier(0);
        MBLK2(Af6, Af7, 6, 7)
    }
#undef MMA2
#undef MBLK2
#undef LDA2
#undef LDB2
#undef STG2

    // ---- epilogue ----
    __builtin_amdgcn_s_barrier();   // all waves past final LDS reads
    if (bn < 2048) {
        char* smb2 = (char*)SM;
#pragma unroll
        for (int mf = 0; mf < 8; ++mf) {
            const int row = wm * 128 + mf * 16 + g * 4;
#pragma unroll
            for (int nf = 0; nf < 4; ++nf) {
                const int col = wn * 64 + nf * 16 + q;
#pragma unroll
                for (int rr = 0; rr < 4; ++rr) {
                    const int r2 = row + rr;
                    *(u16*)(smb2 + r2 * 512 + ((((col >> 3) ^ (r2 & 7))) << 4) + (col & 7) * 2)
                        = f2bf(acc[mf][nf][rr]);
                }
            }
        }
        __syncthreads();
        const int erow = tid >> 1;
        const int ebase = (tid & 1) * 16;
        u16* orow = qkOut + (size_t)(bm + erow) * 2048 + bn;
#pragma unroll
        for (int j = 0; j < 16; ++j) {
            const int s = ebase + j;
            uint4 v = *(const uint4*)(smb2 + erow * 512 + ((s ^ (erow & 7)) << 4));
            *reinterpret_cast<uint4*>(orow + s * 8) = v;
        }
    } else {
        const int colb = bn - 2048 + wn * 64;
        const int bI = bm >> 11;
        const int tIb = (bm & 2047) + wm * 128 + g * 4;
#pragma unroll
        for (int mf = 0; mf < 8; ++mf)
#pragma unroll
            for (int nf = 0; nf < 4; ++nf) {
                const int col = colb + nf * 16 + q;
                uint2 pv;
                pv.x = pk2(acc[mf][nf][0], acc[mf][nf][1]);
                pv.y = pk2(acc[mf][nf][2], acc[mf][nf][3]);
                *reinterpret_cast<uint2*>(
                    &vTOut[((size_t)bI * 1024 + col) * 2048 + tIb + mf * 16]) = pv;
            }
    }
}

// ---------- MFMA flash attention (causal), static-max softmax (r21 verified) ----
// 1024 blocks, one 128-q chunk each, LPT order. Single-buffered K+V LDS.
// Q pre-scaled by C2 (bf16) -> per-element softmax work = one exp2 only.
__global__ __launch_bounds__(256) void attn_mfma(const u16* __restrict__ qk,
                                                 const u16* __restrict__ vT,
                                                 u16* __restrict__ y) {
    __shared__ u16 SM[9216];    // 18,432 B: K [64][72] | V^T [64][72]
    const int tid = threadIdx.x;
    const int w = tid >> 6, l = tid & 63;
    const int q31 = l & 31, hi = l >> 5;
    const int bid = blockIdx.x;
    const int bh = bid & 63;
    const int chunk = 15 - (bid >> 6);        // LPT: big chunks first
    const int b = bh >> 4, h = bh & 15;
    const size_t tok0 = (size_t)b * Tt;

    const float C2 = 0.18033688011112042f;   // 0.125 * log2(e), folded into Q

    const int srow = tid >> 2;
    const int sseg = (tid & 3) * 16;
    const int soff = srow * 72 + sseg;
    const u16* gK = qk + (tok0 + srow) * 2048 + 1024 + h * 64 + sseg;
    const u16* gV = vT + ((size_t)b * 1024 + h * 64 + srow) * 2048 + sseg;

    const int nsteps = 2 * (chunk + 1);
    const int q0w = chunk * 128 + w * 32;
    const int qlane = q0w + q31;

    short8v qf0, qf1, qf2, qf3;
    {
        const u16* qp = qk + (tok0 + qlane) * 2048 + h * 64 + hi * 8;
        qf0 = scale8(*reinterpret_cast<const short8v*>(qp), C2);
        qf1 = scale8(*reinterpret_cast<const short8v*>(qp + 16), C2);
        qf2 = scale8(*reinterpret_cast<const short8v*>(qp + 32), C2);
        qf3 = scale8(*reinterpret_cast<const short8v*>(qp + 48), C2);
    }

    f32x16 acc0 = {}, acc1 = {};
    float l_run = 0.f;

    {   // prologue: stage tile 0
        uint4 ka = *reinterpret_cast<const uint4*>(gK);
        uint4 kb = *reinterpret_cast<const uint4*>(gK + 8);
        uint4 va = *reinterpret_cast<const uint4*>(gV);
        uint4 vb = *reinterpret_cast<const uint4*>(gV + 8);
        *reinterpret_cast<uint4*>(&SM[soff]) = ka;
        *reinterpret_cast<uint4*>(&SM[soff + 8]) = kb;
        *reinterpret_cast<uint4*>(&SM[4608 + soff]) = va;
        *reinterpret_cast<uint4*>(&SM[4608 + soff + 8]) = vb;
    }
    __syncthreads();

    for (int t = 0; t < nsteps; ++t) {
        const int k0 = t * 64;
        const bool pre = (t + 1 < nsteps);
        uint4 ka = {}, kb = {}, va = {}, vb = {};
        if (pre) {
            const u16* gKt = gK + (size_t)(t + 1) * 64 * 2048;
            const u16* gVt = gV + (t + 1) * 64;
            ka = *reinterpret_cast<const uint4*>(gKt);
            kb = *reinterpret_cast<const uint4*>(gKt + 8);
            va = *reinterpret_cast<const uint4*>(gVt);
            vb = *reinterpret_cast<const uint4*>(gVt + 8);
        }

        if (k0 <= q0w + 31) {
            const u16* Kb = SM;
            const u16* Vb = SM + 4608;
            // ---- S' = (C2 Q) K^T via mfma (swapped) ----
            f32x16 st0 = {}, st1 = {};
#pragma unroll
            for (int s = 0; s < 4; ++s) {
                short8v kfa = *reinterpret_cast<const short8v*>(&Kb[q31 * 72 + s * 16 + hi * 8]);
                short8v kfb = *reinterpret_cast<const short8v*>(&Kb[(q31 + 32) * 72 + s * 16 + hi * 8]);
                short8v qs = (s == 0) ? qf0 : (s == 1) ? qf1 : (s == 2) ? qf2 : qf3;
                st0 = __builtin_amdgcn_mfma_f32_32x32x16_bf16(kfa, qs, st0, 0, 0, 0);
                st1 = __builtin_amdgcn_mfma_f32_32x32x16_bf16(kfb, qs, st1, 0, 0, 0);
            }
            // ---- causal mask + exp2 ----
            const bool diag = (k0 + 63 > q0w);
            float s0[16], s1[16];
            float rs = 0.f;
#pragma unroll
            for (int r = 0; r < 16; ++r) {
                int krel = (r & 3) + 8 * (r >> 2) + 4 * hi;
                float v0 = st0[r];
                float v1 = st1[r];
                if (diag) {
                    if (k0 + krel > qlane) v0 = -1e30f;
                    if (k0 + 32 + krel > qlane) v1 = -1e30f;
                }
                float p0 = exp2g(v0);
                float p1 = exp2g(v1);
                s0[r] = p0; s1[r] = p1;
                rs += p0 + p1;
            }
            rs += __shfl_xor(rs, 32);
            l_run += rs;

            // ---- P -> bf16 B-frags via cvt_pk + permlane32_swap ----
            short8v pf0, pf1, pf2, pf3;
#define MKFRAG(dst, P, rb)                                                  \
            {                                                               \
                unsigned int a_ = pk2(P[rb + 0], P[rb + 1]);                \
                unsigned int b_ = pk2(P[rb + 4], P[rb + 5]);                \
                unsigned int c_ = pk2(P[rb + 2], P[rb + 3]);                \
                unsigned int d_ = pk2(P[rb + 6], P[rb + 7]);                \
                plswap(a_, b_);                                             \
                plswap(c_, d_);                                             \
                union { unsigned int u[4]; short8v s; } uf_;                \
                uf_.u[0] = a_; uf_.u[1] = c_; uf_.u[2] = b_; uf_.u[3] = d_; \
                dst = uf_.s;                                                \
            }
            MKFRAG(pf0, s0, 0)
            MKFRAG(pf1, s0, 8)
            MKFRAG(pf2, s1, 0)
            MKFRAG(pf3, s1, 8)
#undef MKFRAG
            // ---- O^T += V^T P^T ----
#pragma unroll
            for (int s = 0; s < 4; ++s) {
                short8v vfa = *reinterpret_cast<const short8v*>(&Vb[q31 * 72 + s * 16 + hi * 8]);
                short8v vfb = *reinterpret_cast<const short8v*>(&Vb[(q31 + 32) * 72 + s * 16 + hi * 8]);
                short8v ps = (s == 0) ? pf0 : (s == 1) ? pf1 : (s == 2) ? pf2 : pf3;
                acc0 = __builtin_amdgcn_mfma_f32_32x32x16_bf16(vfa, ps, acc0, 0, 0, 0);
                acc1 = __builtin_amdgcn_mfma_f32_32x32x16_bf16(vfb, ps, acc1, 0, 0, 0);
            }
        }

        __syncthreads();   // all waves done reading step t
        if (pre) {
            *reinterpret_cast<uint4*>(&SM[soff]) = ka;
            *reinterpret_cast<uint4*>(&SM[soff + 8]) = kb;
            *reinterpret_cast<uint4*>(&SM[4608 + soff]) = va;
            *reinterpret_cast<uint4*>(&SM[4608 + soff + 8]) = vb;
        }
        __syncthreads();   // step t+1 data visible
    }

    // ---- store O: LDS transpose -> coalesced 16B stores ----
    const float inv = 1.f / l_run;
    unsigned int* Od2 = reinterpret_cast<unsigned int*>(SM);
    const int qrow = w * 32 + q31;
#pragma unroll
    for (int r = 0; r < 16; r += 2) {
        int d0 = (r & 3) + 8 * (r >> 2) + 4 * hi;   // even
        Od2[qrow * 36 + (d0 >> 1)] = pk2(acc0[r] * inv, acc0[r + 1] * inv);
        Od2[qrow * 36 + ((32 + d0) >> 1)] = pk2(acc1[r] * inv, acc1[r + 1] * inv);
    }
    __syncthreads();
    {
        const int row = w * 32 + (l >> 1);
        const int dh = (l & 1) * 32;
        const u16* src = SM + row * 72 + dh;
        u16* dst = y + (tok0 + chunk * 128 + row) * Cc + h * 64 + dh;
#pragma unroll
        for (int k2 = 0; k2 < 4; ++k2)
            *reinterpret_cast<uint4*>(dst + k2 * 8) =
                *reinterpret_cast<const uint4*>(src + k2 * 8);
    }
}

extern "C" void kernel_launch(void* const* d_in, const int* in_sizes, int n_in,
                              void* d_out, int out_size, void* d_ws, size_t ws_size,
                              hipStream_t stream) {
    const float* x    = (const float*)d_in[0];
    const float* Wqkv = (const float*)d_in[1];
    const float* Wout = (const float*)d_in[2];
    float* out = (float*)d_out;

    // ws layout (bytes):
    //   qk   bf16 [8192][2048]            @ 0        (33,554,432)
    //   vT   bf16 [4][1024 d][2048 t]     @ 33554432 (16,777,216)
    //   x_bf bf16 [8192][1024] (later y)  @ 50331648 (16,777,216)
    //   WqkvT bf16 [3072][1024]           @ 67108864 ( 6,291,456)
    //   WoutT bf16 [1024][1024]           @ 73400320 ( 2,097,152)
    char* ws = (char*)d_ws;
    u16* qk    = (u16*)(ws);
    u16* vT    = (u16*)(ws + 33554432);
    u16* xbf   = (u16*)(ws + 50331648);  // aliased as y after GEMM1
    u16* WqkvT = (u16*)(ws + 67108864);
    u16* WoutT = (u16*)(ws + 73400320);

    prep<<<8192 + 3072 + 1024, 256, 0, stream>>>(x, xbf, Wqkv, WqkvT, Wout, WoutT);

    gemm256_qkv<<<dim3(Mm / 256, C3 / 256), 512, 0, stream>>>(xbf, WqkvT, qk, vT, Cc);

    u16* ybf = xbf;
    attn_mfma<<<1024, 256, 0, stream>>>(qk, vT, ybf);

    gemm_mfma<1><<<dim3(Mm / 128, Cc / 128), 256, 0, stream>>>(ybf, WoutT, out, Mm, Cc, Cc);
}